// Round 10
// baseline (209.307 us; speedup 1.0000x reference)
//
#include <hip/hip_runtime.h>

// DetectionLoss: B=16, A=65536, T=32, C=21.
// R18: R17 + conf-row PREFETCH in main. The 6 conf VMEM ops were issued
// after phases 1+2 (two barriers) -> waves ate full load latency at point of
// use (VALUBusy 69%, BW 0.92 TB/s = not BW-bound -> latency-stalled). Now the
// row is loaded into registers at kernel start (no deps on phases 1/2), so
// ~1000+ cycles of IoU/LDS work hide it. Unconditional load is side-effect-
// free; identical values/order -> bit-identical output. VGPR ~48->~70, still
// above the 6-block LDS cap's needs.
// Graph: memset, main, tailB(+A), tailC.

#define AN 65536
#define BN 16
#define TN 32
#define CN 21
#define NBA 2048     // anchor/cell L1 bins = focal bits >> 20
#define LCAPG (2 * 65536)   // global per-image cell-list capacity
#define LCAP 10240       // LDS-cached list capacity (40 KB)
#define CHUNK 256
#define BUFC (CHUNK * CN)   // 5376 staged cells max per chunk

struct BlockAcc { float pos_sum; float bbox_sum; unsigned np; unsigned nn; };
struct ImgParams { double pos; double bbox; unsigned np, nn, k, ve, act; };

typedef float f4a __attribute__((ext_vector_type(4), aligned(4)));

// ---------- shared math: bit-identical across kernels (_rn-pinned, shared fns) ----------
__device__ __forceinline__ float box_area(float4 B) {
    return __fmul_rn(__fsub_rn(B.z, B.x), __fsub_rn(B.w, B.y));
}
__device__ __forceinline__ float iou_rcp(float4 A, float aa, float4 T, float ta) {
    float x1 = fmaxf(A.x, T.x), y1 = fmaxf(A.y, T.y);
    float x2 = fminf(A.z, T.z), y2 = fminf(A.w, T.w);
    float inter = __fmul_rn(fmaxf(__fsub_rn(x2, x1), 0.f), fmaxf(__fsub_rn(y2, y1), 0.f));
    float den = __fadd_rn(__fsub_rn(__fadd_rn(aa, ta), inter), 1e-6f);
    return __fmul_rn(inter, __builtin_amdgcn_rcpf(den));
}
__device__ __forceinline__ float row_prep_vals(float* __restrict__ c) {
    float m1[10];
#pragma unroll
    for (int j = 0; j < 10; ++j) m1[j] = fmaxf(c[j], c[j + 10]);
    float m2[5];
#pragma unroll
    for (int j = 0; j < 5; ++j) m2[j] = fmaxf(m1[j], m1[j + 5]);
    float ma = fmaxf(m2[0], m2[1]), mb = fmaxf(m2[2], m2[3]);
    float m = fmaxf(fmaxf(ma, mb), fmaxf(m2[4], c[20]));
#pragma unroll
    for (int j = 0; j < CN; ++j) c[j] = __expf(__fsub_rn(c[j], m));
    float s1[10];
#pragma unroll
    for (int j = 0; j < 10; ++j) s1[j] = __fadd_rn(c[j], c[j + 10]);
    float s2[5];
#pragma unroll
    for (int j = 0; j < 5; ++j) s2[j] = __fadd_rn(s1[j], s1[j + 5]);
    float sa = __fadd_rn(s2[0], s2[1]), sb = __fadd_rn(s2[2], s2[3]);
    float s = __fadd_rn(__fadd_rn(sa, sb), __fadd_rn(s2[4], c[20]));
    return __builtin_amdgcn_rcpf(s);
}
// vectorized row load: 5 x dwordx4 (4B-aligned ok on gfx950) + 1 dword
__device__ __forceinline__ void row_load(const float* __restrict__ row, float* __restrict__ c) {
    const f4a* r4 = (const f4a*)row;
#pragma unroll
    for (int q = 0; q < 5; ++q) {
        f4a v = r4[q];
        c[q * 4 + 0] = v[0]; c[q * 4 + 1] = v[1];
        c[q * 4 + 2] = v[2]; c[q * 4 + 3] = v[3];
    }
    c[20] = row[20];
}
__device__ __forceinline__ float row_prep(const float* __restrict__ row, float* __restrict__ c) {
    row_load(row, c);
    return row_prep_vals(c);
}
__device__ __forceinline__ float cell_focal(float cexp, float inv, bool cellpos) {
    float p = __fmul_rn(cexp, inv);
    float pt = cellpos ? p : __fsub_rn(1.0f, p);
    float af = cellpos ? 0.25f : 0.75f;
    float om = __fsub_rn(1.0f, pt);
    float lg = __logf(fmaxf(pt, 1e-6f));
    return __fmul_rn(__fmul_rn(__fmul_rn(-af, om), om), lg);
}
__device__ __forceinline__ unsigned focal_bits(float fo) {
    unsigned bits = __float_as_uint(fo);
    if (bits == 0x80000000u) bits = 0u;   // canonicalize -0.0
    return bits;
}
__device__ __forceinline__ float bbox_per(float4 b1, float4 b2) {
    float x1 = fmaxf(b1.x, b2.x), y1 = fmaxf(b1.y, b2.y);
    float x2 = fminf(b1.z, b2.z), y2 = fminf(b1.w, b2.w);
    float inter = fmaxf(x2 - x1, 0.f) * fmaxf(y2 - y1, 0.f);
    float a1 = (b1.z - b1.x) * (b1.w - b1.y);
    float a2 = (b2.z - b2.x) * (b2.w - b2.y);
    float un = a1 + a2 - inter;
    float iou = inter / (un + 1e-6f);
    float ex1 = fminf(b1.x, b2.x), ey1 = fminf(b1.y, b2.y);
    float ex2 = fmaxf(b1.z, b2.z), ey2 = fmaxf(b1.w, b2.w);
    float enc = (ex2 - ex1) * (ey2 - ey1);
    float giou = iou - (enc - un) / (enc + 1e-6f);
    float gl = 1.0f - giou;
    float l1 = 0.f, d, ad;
    d = b1.x - b2.x; ad = fabsf(d); l1 += (ad < 1.f) ? (0.5f * d * d) : (ad - 0.5f);
    d = b1.y - b2.y; ad = fabsf(d); l1 += (ad < 1.f) ? (0.5f * d * d) : (ad - 0.5f);
    d = b1.z - b2.z; ad = fabsf(d); l1 += (ad < 1.f) ? (0.5f * d * d) : (ad - 0.5f);
    d = b1.w - b2.w; ad = fabsf(d); l1 += (ad < 1.f) ? (0.5f * d * d) : (ad - 0.5f);
    return gl + 0.5f * (l1 * 0.25f);
}
__device__ __forceinline__ unsigned mbcnt64(unsigned long long m) {
    return __builtin_amdgcn_mbcnt_hi((unsigned)(m >> 32),
           __builtin_amdgcn_mbcnt_lo((unsigned)m, 0u));
}

// ---------- fused main: match + force-argmax + focal + anchor hist ----------
__global__ __launch_bounds__(256) void main_kernel(
    const float* __restrict__ conf, const float4* __restrict__ bboxp,
    const float4* __restrict__ anchors, const float4* __restrict__ tboxes,
    const int* __restrict__ tlabels,
    unsigned long long* __restrict__ gbest,
    unsigned* __restrict__ ahist, unsigned short* __restrict__ maxb,
    BlockAcc* __restrict__ blockAcc)
{
    __shared__ float4 tbS[TN];
    __shared__ int tlS[TN];
    __shared__ float taS[TN];
    __shared__ float iouS[16][260];        // HALF the IoU matrix (16 targets)
    __shared__ unsigned ahp[NBA / 2];      // packed 2 bins/u32
    __shared__ float pbV[TN][8];
    __shared__ int   pbA[TN][8];
    __shared__ float rF[2][4];
    __shared__ unsigned rI[2][4];
    int b = blockIdx.y, tid = threadIdx.x;
    int a = blockIdx.x * 256 + tid;
    size_t idx = (size_t)b * AN + a;

    // PREFETCH: issue the conf-row loads before any barrier; phases 1-2
    // (~1000+ cycles of VALU/LDS, no dependence on conf) hide the latency.
    float c[CN];
    row_load(conf + idx * CN, c);

    for (int i = tid; i < NBA / 2; i += 256) ahp[i] = 0u;
    if (tid < TN) {
        float4 T = tboxes[b * TN + tid];
        tbS[tid] = T; tlS[tid] = tlabels[b * TN + tid]; taS[tid] = box_area(T);
    }
    float4 ab = anchors[a];
    float aa = box_area(ab);
    __syncthreads();

    float best = -1.0f; int bt = 0;
#pragma unroll
    for (int h = 0; h < 2; ++h) {
#pragma unroll
        for (int t2 = 0; t2 < 16; ++t2) {
            int t = h * 16 + t2;
            float iou = iou_rcp(ab, aa, tbS[t], taS[t]);
            iouS[t2][tid] = iou;
            if (iou > best) { best = iou; bt = t; }   // strict >: first occurrence
        }
        __syncthreads();
        if (tid < 128) {
            int t2 = tid & 15, pp = tid >> 4;        // pp in 0..7, 32 anchors each
            const float4* rp = (const float4*)(&iouS[t2][pp * 32]);
            float bv = -1.f; int ba = 0;
#pragma unroll
            for (int q = 0; q < 8; ++q) {
                float4 v4 = rp[q];
                int i0 = pp * 32 + q * 4;
                if (v4.x > bv) { bv = v4.x; ba = i0 + 0; }
                if (v4.y > bv) { bv = v4.y; ba = i0 + 1; }
                if (v4.z > bv) { bv = v4.z; ba = i0 + 2; }
                if (v4.w > bv) { bv = v4.w; ba = i0 + 3; }
            }
            pbV[h * 16 + t2][pp] = bv; pbA[h * 16 + t2][pp] = ba;
        }
        __syncthreads();   // protect iouS reuse by next chunk
    }
    if (tid < TN) {
        float bv = -1.f; int ba = 0;
#pragma unroll
        for (int pp = 0; pp < 8; ++pp) {
            float v = pbV[tid][pp];
            if (v > bv) { bv = v; ba = pbA[tid][pp]; }   // ascending anchor ranges
        }
        unsigned ga = blockIdx.x * 256 + (unsigned)ba;
        unsigned long long key =
            (((unsigned long long)__float_as_uint(bv)) << 32) | (unsigned long long)(unsigned)(~ga);
        atomicMax(&gbest[b * TN + tid], key);   // tie -> smaller anchor idx
    }

    bool posA = best >= 0.5f;
    bool negA = best < 0.4f;
    float fs = 0.f, bper = 0.f;
    unsigned short mbenc = 0;
    if (posA || negA) {
        float inv = row_prep_vals(c);
        if (posA) {
            int label = tlS[bt];
#pragma unroll
            for (int j = 0; j < CN; ++j) fs += cell_focal(c[j], inv, j == label);
            bper = bbox_per(bboxp[idx], tbS[bt]);
        } else {
            // neg: max_j focal_j == focal(max_j c_j), and max_j c_j == 1.0f
            float fo = cell_focal(1.0f, inv, false);
            unsigned bin = focal_bits(fo) >> 20;      // 0..2047
            mbenc = (unsigned short)(bin + 1u);       // 0 = not-neg
            atomicAdd(&ahp[bin >> 1], 1u << ((bin & 1) << 4));
        }
    }
    maxb[idx] = mbenc;

    float vpos = posA ? fs : 0.f, vb = bper;
    unsigned inp = posA ? 1u : 0u, inn = negA ? 1u : 0u;
#pragma unroll
    for (int off = 32; off; off >>= 1) {
        vpos += __shfl_down(vpos, off, 64);
        vb   += __shfl_down(vb,   off, 64);
        inp  += __shfl_down(inp,  off, 64);
        inn  += __shfl_down(inn,  off, 64);
    }
    int wv = tid >> 6, ln = tid & 63;
    if (ln == 0) { rF[0][wv] = vpos; rF[1][wv] = vb; rI[0][wv] = inp; rI[1][wv] = inn; }
    __syncthreads();
    if (tid == 0) {
        BlockAcc ba2;
        ba2.pos_sum = rF[0][0] + rF[0][1] + rF[0][2] + rF[0][3];
        ba2.bbox_sum = rF[1][0] + rF[1][1] + rF[1][2] + rF[1][3];
        ba2.np = rI[0][0] + rI[0][1] + rI[0][2] + rI[0][3];
        ba2.nn = rI[1][0] + rI[1][1] + rI[1][2] + rI[1][3];
        blockAcc[b * 256 + blockIdx.x] = ba2;
    }
    for (int i = tid; i < NBA / 2; i += 256) {
        unsigned v = ahp[i];
        if (v) {
            if (v & 0xFFFFu) atomicAdd(&ahist[b * NBA + 2 * i], v & 0xFFFFu);
            if (v >> 16)     atomicAdd(&ahist[b * NBA + 2 * i + 1], v >> 16);
        }
    }
}

// ---------- tailB(+A): per-block redundant params recompute + compact + cell list ----------
// grid (64, BN) x 256 threads: each block owns 1024 anchors of one image.
__global__ __launch_bounds__(256) void tailB_kernel(
    const float* __restrict__ conf, const float4* __restrict__ bboxp,
    const float4* __restrict__ anchors, const float4* __restrict__ tboxes,
    const int* __restrict__ tlabels,
    const unsigned long long* __restrict__ gbest,
    const BlockAcc* __restrict__ blockAcc,
    const unsigned* __restrict__ ahist, const unsigned short* __restrict__ maxb,
    ImgParams* __restrict__ params,
    float* __restrict__ list, unsigned* __restrict__ listCnt)
{
    __shared__ unsigned hist[NBA];         // local copy; undo applied locally
    __shared__ unsigned scanL[256];
    __shared__ float4 tbS[TN];
    __shared__ int tlS[TN];
    __shared__ float taS[TN];
    __shared__ unsigned gaS[TN];
    __shared__ float dps[TN], dbb[TN];
    __shared__ int dnp[TN], dnn[TN];
    __shared__ unsigned undoS[TN], undoIR[TN];
    __shared__ double sdblP[4], sdblB[4];
    __shared__ unsigned sunsP[4], sunsB[4];
    __shared__ double s_pos, s_bbox;
    __shared__ unsigned s_np, s_nn, s_k, s_act, s_ve, s_undoCnt, s_irCnt;
    __shared__ int candS[1024];
    __shared__ unsigned bufS[BUFC];
    __shared__ unsigned s_cnt, s_bcnt, s_gbase;

    int b = blockIdx.y, tid = threadIdx.x;
    int wv = tid >> 6, ln = tid & 63;

    for (int i = tid; i < NBA; i += 256) hist[i] = ahist[b * NBA + i];
    if (tid < TN) {
        gaS[tid] = ~(unsigned)(gbest[b * TN + tid] & 0xFFFFFFFFull);
        float4 T = tboxes[b * TN + tid];
        tbS[tid] = T; tlS[tid] = tlabels[b * TN + tid]; taS[tid] = box_area(T);
        dps[tid] = 0.f; dbb[tid] = 0.f; dnp[tid] = 0; dnn[tid] = 0;
    }
    if (tid == 0) { s_undoCnt = 0u; s_irCnt = 0u; s_cnt = 0u; }
    __syncthreads();

    // ---- phase A (redundant per block, deterministic): force-match fix ----
    if (tid < TN) {
        bool doit = true;
        unsigned ga = gaS[tid];
        for (int u = 0; u < tid; ++u) if (gaS[u] == ga) doit = false;   // dedupe
        if (doit) {
            size_t idx = (size_t)b * AN + ga;
            float4 ab = anchors[ga];
            float aa = box_area(ab);
            float best = -1.f; int bt = 0;
#pragma unroll
            for (int t = 0; t < TN; ++t) {
                float iou = iou_rcp(ab, aa, tbS[t], taS[t]);   // bit-identical to main
                if (iou > best) { best = iou; bt = t; }
            }
            if (best < 0.5f) {
                int label = tlS[bt];
                float c[CN];
                float inv = row_prep(conf + idx * CN, c);
                float fsv = 0.f;
#pragma unroll
                for (int j = 0; j < CN; ++j) fsv += cell_focal(c[j], inv, j == label);
                dps[tid] = fsv;
                dbb[tid] = bbox_per(bboxp[idx], tbS[bt]);
                dnp[tid] = 1;
                if (best < 0.4f) {   // was counted neg: undo locally
                    unsigned enc = maxb[idx];        // bin+1
                    atomicSub(&hist[enc - 1u], 1u);
                    dnn[tid] = -1;
                    unsigned p = atomicAdd(&s_undoCnt, 1u);
                    undoS[p] = ga;                   // global anchor idx to exclude
                }
            }
        }
    }
    __syncthreads();

    // ---- phase B: totals (256 threads, 1 BlockAcc each; same tree/order) ----
    {
        BlockAcc ba = blockAcc[b * 256 + tid];
        double ps = (double)ba.pos_sum, bs = (double)ba.bbox_sum;
        unsigned np = ba.np, nn = ba.nn;
#pragma unroll
        for (int off = 32; off; off >>= 1) {
            ps += __shfl_down(ps, off, 64);
            bs += __shfl_down(bs, off, 64);
            np += __shfl_down(np, off, 64);
            nn += __shfl_down(nn, off, 64);
        }
        if (ln == 0) { sdblP[wv] = ps; sdblB[wv] = bs; sunsP[wv] = np; sunsB[wv] = nn; }
    }
    __syncthreads();
    if (tid == 0) {
        double dp = 0, db = 0; int cp = 0, cn = 0;
        for (int i = 0; i < TN; ++i) { dp += dps[i]; db += dbb[i]; cp += dnp[i]; cn += dnn[i]; }
        s_pos = sdblP[0] + sdblP[1] + sdblP[2] + sdblP[3] + dp;
        s_bbox = sdblB[0] + sdblB[1] + sdblB[2] + sdblB[3] + db;
        unsigned NP = (unsigned)((int)(sunsP[0] + sunsP[1] + sunsP[2] + sunsP[3]) + cp);
        unsigned NN = (unsigned)((int)(sunsB[0] + sunsB[1] + sunsB[2] + sunsB[3]) + cn);
        s_np = NP; s_nn = NN;
        unsigned k = min(3u * NP, NN);
        s_k = k;
        s_act = (NN > 0 && k > 0) ? 1u : 0u;
        s_ve = 0u;
    }
    __syncthreads();

    if (s_act) {
        unsigned k = s_k;
        // ---- phase C: anchor-max threshold (2048 bins, 8/thread, suffix scan) ----
        unsigned l8[8], cc = 0;
#pragma unroll
        for (int q = 0; q < 8; ++q) { l8[q] = hist[tid * 8 + q]; cc += l8[q]; }
        scanL[tid] = cc;
        __syncthreads();
        for (int off = 1; off < 256; off <<= 1) {
            unsigned v = (tid + off < 256) ? scanL[tid + off] : 0u;
            __syncthreads();
            scanL[tid] += v;
            __syncthreads();
        }
        {
            unsigned above = (tid < 255) ? scanL[tid + 1] : 0u;
            if (above < k && above + cc >= k) {
                unsigned a2 = above;
                for (int q = 7; q >= 0; --q) {
                    unsigned bc = l8[q];
                    if (a2 + bc >= k) { s_ve = ((unsigned)(tid * 8 + q) << 21) | 1u; break; }
                    a2 += bc;
                }
            }
        }
        __syncthreads();
    }
    if (blockIdx.x == 0 && tid == 0) {
        ImgParams P;
        P.pos = s_pos; P.bbox = s_bbox;
        P.np = s_np; P.nn = s_nn; P.k = s_k; P.ve = s_ve; P.act = s_act;
        params[b] = P;
    }
    if (!s_act) return;   // uniform per block

    unsigned ve = s_ve;
    unsigned vbits = ve >> 1;
    unsigned short tb16 = (unsigned short)((ve >> 21) + 1u);   // candidate iff enc16 >= tb16
    int base = blockIdx.x * 1024;

    // filter undo list to this block's range (usually 0-1 entries)
    unsigned uc = s_undoCnt;
    if (tid < uc) {
        unsigned e = undoS[tid];
        if (e >= (unsigned)base && e < (unsigned)(base + 1024)) {
            unsigned p = atomicAdd(&s_irCnt, 1u);
            undoIR[p] = e;
        }
    }
    __syncthreads();
    unsigned ir = s_irCnt;

    const ushort4* mb4 = (const ushort4*)(maxb + (size_t)b * AN + base);
    ushort4 m4 = mb4[tid];
    unsigned c0 = (m4.x >= tb16), c1 = (m4.y >= tb16), c2 = (m4.z >= tb16), c3 = (m4.w >= tb16);
    int a0 = base + tid * 4;
    for (unsigned u = 0; u < ir; ++u) {     // exclude undone forced anchors
        unsigned e = undoIR[u];
        if (e == (unsigned)a0)          c0 = 0;
        else if (e == (unsigned)a0 + 1) c1 = 0;
        else if (e == (unsigned)a0 + 2) c2 = 0;
        else if (e == (unsigned)a0 + 3) c3 = 0;
    }
    unsigned cnt = c0 + c1 + c2 + c3;
    unsigned pos = 0;
    if (cnt) pos = atomicAdd(&s_cnt, cnt);
    if (c0) candS[pos++] = a0 + 0;
    if (c1) candS[pos++] = a0 + 1;
    if (c2) candS[pos++] = a0 + 2;
    if (c3) candS[pos++] = a0 + 3;
    __syncthreads();
    unsigned n = s_cnt;

    for (unsigned cbase = 0; cbase < n; cbase += CHUNK) {
        if (tid == 0) s_bcnt = 0u;
        __syncthreads();
        unsigned i = cbase + tid;
        if (i < n) {
            int a = candS[i];
            size_t idx = (size_t)b * AN + a;
            float c[CN];
            float inv = row_prep(conf + idx * CN, c);
#pragma unroll
            for (int j = 0; j < CN; ++j) {
                float fo = cell_focal(c[j], inv, false);
                unsigned bits = focal_bits(fo);
                bool hit = bits >= vbits;
                unsigned long long msk = __ballot(hit);
                if (hit) {
                    unsigned pre = mbcnt64(msk);
                    unsigned bb = 0;
                    if (pre == 0) bb = atomicAdd(&s_bcnt, (unsigned)__popcll(msk));
                    bb = __shfl(bb, (int)(__ffsll((long long)msk) - 1), 64);
                    bufS[bb + pre] = bits;   // canonicalized focal bits
                }
            }
        }
        __syncthreads();
        unsigned ccnt = s_bcnt;
        if (ccnt) {
            if (tid == 0) s_gbase = atomicAdd(&listCnt[b * 16], ccnt);  // 64B-padded counter
            __syncthreads();
            unsigned gb = s_gbase;
            for (unsigned j2 = tid; j2 < ccnt; j2 += 256) {
                unsigned p = gb + j2;
                if (p < (unsigned)LCAPG)
                    list[(size_t)b * LCAPG + p] = __uint_as_float(bufS[j2]);
            }
        }
        __syncthreads();
    }
}

// ---------- tailC: top-k select over compact list + per-image result + average ----------
__global__ __launch_bounds__(1024) void tailC_kernel(
    const float* __restrict__ list, const unsigned* __restrict__ listCnt,
    const ImgParams* __restrict__ params,
    double* __restrict__ imgRes, unsigned* __restrict__ ctr,
    float* __restrict__ out)
{
    __shared__ float lcache[LCAP];      // 40 KB
    __shared__ unsigned hist[4096];
    __shared__ unsigned scan_[1024];
    __shared__ double sdbl[16];
    __shared__ double s_sumAbove;
    __shared__ unsigned s_b1, s_rem, s_b2, s_rem2, s_b3, s_rem3;

    int b = blockIdx.x, tid = threadIdx.x;
    int wv = tid >> 6, ln = tid & 63;
    ImgParams P = params[b];
    double topk = 0.0;

    if (P.act) {
        unsigned n = min(listCnt[b * 16], (unsigned)LCAPG);
        const float* gl = list + (size_t)b * LCAPG;
        bool inL = (n <= (unsigned)LCAP);
        if (inL) for (unsigned i = tid; i < n; i += 1024) lcache[i] = gl[i];
        if (tid == 0) { s_b1 = 0; s_rem = 0; s_b3 = 0; s_rem3 = 0; }
        for (int i = tid; i < 4096; i += 1024) hist[i] = 0u;
        __syncthreads();

        // pass 0: 2048-bin hist over top bits (focal >= 0 -> bits>>20 < 2048)
        for (unsigned i = tid; i < n; i += 1024) {
            unsigned bits = __float_as_uint(inL ? lcache[i] : gl[i]);
            atomicAdd(&hist[bits >> 20], 1u);
        }
        __syncthreads();

        // select b1 (suffix scan, 2 bins/thread)
        unsigned lc0 = hist[tid * 2], lc1 = hist[tid * 2 + 1];
        unsigned cc = lc0 + lc1;
        scan_[tid] = cc;
        __syncthreads();
        for (int off = 1; off < 1024; off <<= 1) {
            unsigned v = (tid + off < 1024) ? scan_[tid + off] : 0u;
            __syncthreads();
            scan_[tid] += v;
            __syncthreads();
        }
        {
            unsigned total = scan_[0];
            unsigned above = (tid < 1023) ? scan_[tid + 1] : 0u;
            unsigned r = min(P.k, total);
            if (r > 0 && above < r && above + cc >= r) {
                if (above + lc1 >= r) { s_b1 = (unsigned)(tid * 2 + 1); s_rem = r - above; }
                else { s_b1 = (unsigned)(tid * 2); s_rem = r - above - lc1; }
            }
        }
        __syncthreads();
        unsigned b1 = s_b1, rem = s_rem;

        // pass 1: sumAbove (hi > b1) + 12-bit sub-hist for hi == b1
        for (int i = tid; i < 4096; i += 1024) hist[i] = 0u;
        __syncthreads();
        double sA = 0.0;
        for (unsigned i = tid; i < n; i += 1024) {
            float v = inL ? lcache[i] : gl[i];
            unsigned bits = __float_as_uint(v);
            unsigned hi = bits >> 20;
            if (hi > b1) sA += (double)v;
            else if (hi == b1) atomicAdd(&hist[(bits >> 8) & 0xFFFu], 1u);
        }
#pragma unroll
        for (int off = 32; off; off >>= 1) sA += __shfl_down(sA, off, 64);
        if (ln == 0) sdbl[wv] = sA;
        __syncthreads();
        if (tid == 0) {
            double tt = 0;
            for (int w = 0; w < 16; ++w) tt += sdbl[w];
            s_sumAbove = tt;
        }
        __syncthreads();
        double sumAbove = s_sumAbove;

        if (rem == 0) {
            topk = sumAbove;
        } else {
            // select b2 from 4096-bin hist (4 bins/thread)
            unsigned l4[4], cc4 = 0;
#pragma unroll
            for (int q = 0; q < 4; ++q) { l4[q] = hist[tid * 4 + q]; cc4 += l4[q]; }
            scan_[tid] = cc4;
            __syncthreads();
            for (int off = 1; off < 1024; off <<= 1) {
                unsigned v = (tid + off < 1024) ? scan_[tid + off] : 0u;
                __syncthreads();
                scan_[tid] += v;
                __syncthreads();
            }
            {
                unsigned total = scan_[0];
                unsigned above = (tid < 1023) ? scan_[tid + 1] : 0u;
                unsigned r = min(rem, total);
                if (above < r && above + cc4 >= r) {
                    unsigned a2 = above;
                    for (int i = 3; i >= 0; --i) {
                        unsigned bc = l4[i];
                        if (a2 + bc >= r) { s_b2 = (unsigned)(tid * 4 + i); s_rem2 = r - a2; break; }
                        a2 += bc;
                    }
                }
            }
            __syncthreads();
            unsigned b2 = s_b2, rem2 = s_rem2;
            if (tid < 256) hist[tid] = 0u;
            __syncthreads();

            // pass 2: sMid (sub > b2) + 8-bit hist for sub == b2
            double sMid = 0.0;
            for (unsigned i = tid; i < n; i += 1024) {
                float v = inL ? lcache[i] : gl[i];
                unsigned bits = __float_as_uint(v);
                if ((bits >> 20) != b1) continue;
                unsigned sub = (bits >> 8) & 0xFFFu;
                if (sub > b2) sMid += (double)v;
                else if (sub == b2) atomicAdd(&hist[bits & 0xFFu], 1u);
            }
            __syncthreads();
            if (tid < 256) scan_[tid] = hist[tid];
            __syncthreads();
            for (int off = 1; off < 256; off <<= 1) {
                unsigned v = 0;
                if (tid < 256 && tid + off < 256) v = scan_[tid + off];
                __syncthreads();
                if (tid < 256) scan_[tid] += v;
                __syncthreads();
            }
            if (tid < 256) {
                unsigned above8 = (tid < 255) ? scan_[tid + 1] : 0u;
                unsigned c8 = hist[tid];
                if (above8 < rem2 && above8 + c8 >= rem2) { s_b3 = (unsigned)tid; s_rem3 = rem2 - above8; }
            }
            __syncthreads();
            unsigned b3 = s_b3, rem3 = s_rem3;

            // pass 3: s3 for (b1,b2, low > b3)
            double s3 = 0.0;
            for (unsigned i = tid; i < n; i += 1024) {
                float v = inL ? lcache[i] : gl[i];
                unsigned bits = __float_as_uint(v);
                if ((bits >> 20) == b1 && ((bits >> 8) & 0xFFFu) == b2 && (bits & 0xFFu) > b3)
                    s3 += (double)v;
            }
            double tot = sMid + s3;
#pragma unroll
            for (int off = 32; off; off >>= 1) tot += __shfl_down(tot, off, 64);
            if (ln == 0) sdbl[wv] = tot;
            __syncthreads();
            if (tid == 0) {
                double totAll = 0;
                for (int w = 0; w < 16; ++w) totAll += sdbl[w];
                unsigned vb3 = (b1 << 20) | (b2 << 8) | b3;
                topk = sumAbove + totAll + (double)rem3 * (double)__uint_as_float(vb3);
            }
        }
    }

    // ---- per-image result + last-block average ----
    if (tid == 0) {
        double confl;
        if (P.act) confl = (P.pos + topk) / (double)max(P.np + P.k, 1u);
        else       confl = P.pos / (double)max(P.np, 1u);
        imgRes[b * 2 + 0] = confl;
        imgRes[b * 2 + 1] = P.bbox / (double)max(P.np, 1u);
        __threadfence();
        unsigned prev = atomicAdd(ctr, 1u);
        if (prev == BN - 1) {
            __threadfence();
            double cs = 0, bs = 0;
            for (int i = 0; i < BN; ++i) { cs += imgRes[i * 2]; bs += imgRes[i * 2 + 1]; }
            cs /= BN; bs /= BN;
            out[0] = (float)(cs + bs);
            out[1] = (float)cs;
            out[2] = (float)bs;
        }
    }
}

extern "C" void kernel_launch(void* const* d_in, const int* in_sizes, int n_in,
                              void* d_out, int out_size, void* d_ws, size_t ws_size,
                              hipStream_t stream)
{
    (void)in_sizes; (void)n_in; (void)out_size; (void)ws_size;
    const float*  conf    = (const float*)d_in[0];
    const float4* bboxp   = (const float4*)d_in[1];
    const float4* anchors = (const float4*)d_in[2];
    const float4* tboxes  = (const float4*)d_in[3];
    const int*    tlabels = (const int*)d_in[4];
    float* out = (float*)d_out;
    char* ws = (char*)d_ws;
    size_t off = 0;
    auto alloc = [&](size_t bytes) -> void* {
        void* p = (void*)(ws + off);
        off = (off + bytes + 255) & ~(size_t)255;
        return p;
    };
    unsigned short* maxb = (unsigned short*)alloc((size_t)BN * AN * 2);
    float*     list     = (float*)alloc((size_t)BN * LCAPG * 4);
    BlockAcc*  blockAcc = (BlockAcc*)alloc((size_t)BN * 256 * sizeof(BlockAcc));
    double*    imgRes   = (double*)alloc((size_t)BN * 2 * 8);
    ImgParams* params   = (ImgParams*)alloc((size_t)BN * sizeof(ImgParams));
    size_t zstart = off;
    unsigned long long* gbest = (unsigned long long*)alloc((size_t)BN * TN * 8);
    unsigned* ahist   = (unsigned*)alloc((size_t)BN * NBA * 4);
    unsigned* ctr     = (unsigned*)alloc(256);
    unsigned* listCnt = (unsigned*)alloc((size_t)BN * 16 * 4);   // 64B stride per image
    size_t zbytes = off - zstart;
    hipMemsetAsync(ws + zstart, 0, zbytes, stream);

    dim3 gridA(AN / 256, BN);
    main_kernel<<<gridA, 256, 0, stream>>>(conf, bboxp, anchors, tboxes, tlabels,
                                           gbest, ahist, maxb, blockAcc);
    tailB_kernel<<<dim3(64, BN), 256, 0, stream>>>(conf, bboxp, anchors, tboxes, tlabels,
                                                   gbest, blockAcc, ahist, maxb,
                                                   params, list, listCnt);
    tailC_kernel<<<BN, 1024, 0, stream>>>(list, listCnt, params, imgRes, ctr, out);
}

// Round 11
// 201.576 us; speedup vs baseline: 1.0384x; 1.0384x over previous
//
#include <hip/hip_runtime.h>

// DetectionLoss: B=16, A=65536, T=32, C=21.
// R19: exact REVERT of R18's conf prefetch (regressed 57->84us main: 21 VGPRs
// pinned across both barriers + coordinated kernel-start VMEM burst beat the
// naturally staggered point-of-use issue; VALUBusy 69->47 = more stall).
// This is R17 verbatim -- the measured-best configuration (202.0us):
// memset, main (R16 structure), tailB(+A redundant recompute), tailC.

#define AN 65536
#define BN 16
#define TN 32
#define CN 21
#define NBA 2048     // anchor/cell L1 bins = focal bits >> 20
#define LCAPG (2 * 65536)   // global per-image cell-list capacity
#define LCAP 10240       // LDS-cached list capacity (40 KB)
#define CHUNK 256
#define BUFC (CHUNK * CN)   // 5376 staged cells max per chunk

struct BlockAcc { float pos_sum; float bbox_sum; unsigned np; unsigned nn; };
struct ImgParams { double pos; double bbox; unsigned np, nn, k, ve, act; };

typedef float f4a __attribute__((ext_vector_type(4), aligned(4)));

// ---------- shared math: bit-identical across kernels (_rn-pinned, shared fns) ----------
__device__ __forceinline__ float box_area(float4 B) {
    return __fmul_rn(__fsub_rn(B.z, B.x), __fsub_rn(B.w, B.y));
}
__device__ __forceinline__ float iou_rcp(float4 A, float aa, float4 T, float ta) {
    float x1 = fmaxf(A.x, T.x), y1 = fmaxf(A.y, T.y);
    float x2 = fminf(A.z, T.z), y2 = fminf(A.w, T.w);
    float inter = __fmul_rn(fmaxf(__fsub_rn(x2, x1), 0.f), fmaxf(__fsub_rn(y2, y1), 0.f));
    float den = __fadd_rn(__fsub_rn(__fadd_rn(aa, ta), inter), 1e-6f);
    return __fmul_rn(inter, __builtin_amdgcn_rcpf(den));
}
__device__ __forceinline__ float row_prep_vals(float* __restrict__ c) {
    float m1[10];
#pragma unroll
    for (int j = 0; j < 10; ++j) m1[j] = fmaxf(c[j], c[j + 10]);
    float m2[5];
#pragma unroll
    for (int j = 0; j < 5; ++j) m2[j] = fmaxf(m1[j], m1[j + 5]);
    float ma = fmaxf(m2[0], m2[1]), mb = fmaxf(m2[2], m2[3]);
    float m = fmaxf(fmaxf(ma, mb), fmaxf(m2[4], c[20]));
#pragma unroll
    for (int j = 0; j < CN; ++j) c[j] = __expf(__fsub_rn(c[j], m));
    float s1[10];
#pragma unroll
    for (int j = 0; j < 10; ++j) s1[j] = __fadd_rn(c[j], c[j + 10]);
    float s2[5];
#pragma unroll
    for (int j = 0; j < 5; ++j) s2[j] = __fadd_rn(s1[j], s1[j + 5]);
    float sa = __fadd_rn(s2[0], s2[1]), sb = __fadd_rn(s2[2], s2[3]);
    float s = __fadd_rn(__fadd_rn(sa, sb), __fadd_rn(s2[4], c[20]));
    return __builtin_amdgcn_rcpf(s);
}
// vectorized row load: 5 x dwordx4 (4B-aligned ok on gfx950) + 1 dword
__device__ __forceinline__ float row_prep(const float* __restrict__ row, float* __restrict__ c) {
    const f4a* r4 = (const f4a*)row;
#pragma unroll
    for (int q = 0; q < 5; ++q) {
        f4a v = r4[q];
        c[q * 4 + 0] = v[0]; c[q * 4 + 1] = v[1];
        c[q * 4 + 2] = v[2]; c[q * 4 + 3] = v[3];
    }
    c[20] = row[20];
    return row_prep_vals(c);
}
__device__ __forceinline__ float cell_focal(float cexp, float inv, bool cellpos) {
    float p = __fmul_rn(cexp, inv);
    float pt = cellpos ? p : __fsub_rn(1.0f, p);
    float af = cellpos ? 0.25f : 0.75f;
    float om = __fsub_rn(1.0f, pt);
    float lg = __logf(fmaxf(pt, 1e-6f));
    return __fmul_rn(__fmul_rn(__fmul_rn(-af, om), om), lg);
}
__device__ __forceinline__ unsigned focal_bits(float fo) {
    unsigned bits = __float_as_uint(fo);
    if (bits == 0x80000000u) bits = 0u;   // canonicalize -0.0
    return bits;
}
__device__ __forceinline__ float bbox_per(float4 b1, float4 b2) {
    float x1 = fmaxf(b1.x, b2.x), y1 = fmaxf(b1.y, b2.y);
    float x2 = fminf(b1.z, b2.z), y2 = fminf(b1.w, b2.w);
    float inter = fmaxf(x2 - x1, 0.f) * fmaxf(y2 - y1, 0.f);
    float a1 = (b1.z - b1.x) * (b1.w - b1.y);
    float a2 = (b2.z - b2.x) * (b2.w - b2.y);
    float un = a1 + a2 - inter;
    float iou = inter / (un + 1e-6f);
    float ex1 = fminf(b1.x, b2.x), ey1 = fminf(b1.y, b2.y);
    float ex2 = fmaxf(b1.z, b2.z), ey2 = fmaxf(b1.w, b2.w);
    float enc = (ex2 - ex1) * (ey2 - ey1);
    float giou = iou - (enc - un) / (enc + 1e-6f);
    float gl = 1.0f - giou;
    float l1 = 0.f, d, ad;
    d = b1.x - b2.x; ad = fabsf(d); l1 += (ad < 1.f) ? (0.5f * d * d) : (ad - 0.5f);
    d = b1.y - b2.y; ad = fabsf(d); l1 += (ad < 1.f) ? (0.5f * d * d) : (ad - 0.5f);
    d = b1.z - b2.z; ad = fabsf(d); l1 += (ad < 1.f) ? (0.5f * d * d) : (ad - 0.5f);
    d = b1.w - b2.w; ad = fabsf(d); l1 += (ad < 1.f) ? (0.5f * d * d) : (ad - 0.5f);
    return gl + 0.5f * (l1 * 0.25f);
}
__device__ __forceinline__ unsigned mbcnt64(unsigned long long m) {
    return __builtin_amdgcn_mbcnt_hi((unsigned)(m >> 32),
           __builtin_amdgcn_mbcnt_lo((unsigned)m, 0u));
}

// ---------- fused main: match + force-argmax + focal + anchor hist (R16, unchanged) ----------
__global__ __launch_bounds__(256) void main_kernel(
    const float* __restrict__ conf, const float4* __restrict__ bboxp,
    const float4* __restrict__ anchors, const float4* __restrict__ tboxes,
    const int* __restrict__ tlabels,
    unsigned long long* __restrict__ gbest,
    unsigned* __restrict__ ahist, unsigned short* __restrict__ maxb,
    BlockAcc* __restrict__ blockAcc)
{
    __shared__ float4 tbS[TN];
    __shared__ int tlS[TN];
    __shared__ float taS[TN];
    __shared__ float iouS[16][260];        // HALF the IoU matrix (16 targets)
    __shared__ unsigned ahp[NBA / 2];      // packed 2 bins/u32
    __shared__ float pbV[TN][8];
    __shared__ int   pbA[TN][8];
    __shared__ float rF[2][4];
    __shared__ unsigned rI[2][4];
    int b = blockIdx.y, tid = threadIdx.x;
    int a = blockIdx.x * 256 + tid;
    for (int i = tid; i < NBA / 2; i += 256) ahp[i] = 0u;
    if (tid < TN) {
        float4 T = tboxes[b * TN + tid];
        tbS[tid] = T; tlS[tid] = tlabels[b * TN + tid]; taS[tid] = box_area(T);
    }
    float4 ab = anchors[a];
    float aa = box_area(ab);
    __syncthreads();

    float best = -1.0f; int bt = 0;
#pragma unroll
    for (int h = 0; h < 2; ++h) {
#pragma unroll
        for (int t2 = 0; t2 < 16; ++t2) {
            int t = h * 16 + t2;
            float iou = iou_rcp(ab, aa, tbS[t], taS[t]);
            iouS[t2][tid] = iou;
            if (iou > best) { best = iou; bt = t; }   // strict >: first occurrence
        }
        __syncthreads();
        if (tid < 128) {
            int t2 = tid & 15, pp = tid >> 4;        // pp in 0..7, 32 anchors each
            const float4* rp = (const float4*)(&iouS[t2][pp * 32]);
            float bv = -1.f; int ba = 0;
#pragma unroll
            for (int q = 0; q < 8; ++q) {
                float4 v4 = rp[q];
                int i0 = pp * 32 + q * 4;
                if (v4.x > bv) { bv = v4.x; ba = i0 + 0; }
                if (v4.y > bv) { bv = v4.y; ba = i0 + 1; }
                if (v4.z > bv) { bv = v4.z; ba = i0 + 2; }
                if (v4.w > bv) { bv = v4.w; ba = i0 + 3; }
            }
            pbV[h * 16 + t2][pp] = bv; pbA[h * 16 + t2][pp] = ba;
        }
        __syncthreads();   // protect iouS reuse by next chunk
    }
    if (tid < TN) {
        float bv = -1.f; int ba = 0;
#pragma unroll
        for (int pp = 0; pp < 8; ++pp) {
            float v = pbV[tid][pp];
            if (v > bv) { bv = v; ba = pbA[tid][pp]; }   // ascending anchor ranges
        }
        unsigned ga = blockIdx.x * 256 + (unsigned)ba;
        unsigned long long key =
            (((unsigned long long)__float_as_uint(bv)) << 32) | (unsigned long long)(unsigned)(~ga);
        atomicMax(&gbest[b * TN + tid], key);   // tie -> smaller anchor idx
    }

    size_t idx = (size_t)b * AN + a;
    bool posA = best >= 0.5f;
    bool negA = best < 0.4f;
    float fs = 0.f, bper = 0.f;
    unsigned short mbenc = 0;
    if (posA || negA) {
        float c[CN];
        float inv = row_prep(conf + idx * CN, c);
        if (posA) {
            int label = tlS[bt];
#pragma unroll
            for (int j = 0; j < CN; ++j) fs += cell_focal(c[j], inv, j == label);
            bper = bbox_per(bboxp[idx], tbS[bt]);
        } else {
            // neg: max_j focal_j == focal(max_j c_j), and max_j c_j == 1.0f
            float fo = cell_focal(1.0f, inv, false);
            unsigned bin = focal_bits(fo) >> 20;      // 0..2047
            mbenc = (unsigned short)(bin + 1u);       // 0 = not-neg
            atomicAdd(&ahp[bin >> 1], 1u << ((bin & 1) << 4));
        }
    }
    maxb[idx] = mbenc;

    float vpos = posA ? fs : 0.f, vb = bper;
    unsigned inp = posA ? 1u : 0u, inn = negA ? 1u : 0u;
#pragma unroll
    for (int off = 32; off; off >>= 1) {
        vpos += __shfl_down(vpos, off, 64);
        vb   += __shfl_down(vb,   off, 64);
        inp  += __shfl_down(inp,  off, 64);
        inn  += __shfl_down(inn,  off, 64);
    }
    int wv = tid >> 6, ln = tid & 63;
    if (ln == 0) { rF[0][wv] = vpos; rF[1][wv] = vb; rI[0][wv] = inp; rI[1][wv] = inn; }
    __syncthreads();
    if (tid == 0) {
        BlockAcc ba2;
        ba2.pos_sum = rF[0][0] + rF[0][1] + rF[0][2] + rF[0][3];
        ba2.bbox_sum = rF[1][0] + rF[1][1] + rF[1][2] + rF[1][3];
        ba2.np = rI[0][0] + rI[0][1] + rI[0][2] + rI[0][3];
        ba2.nn = rI[1][0] + rI[1][1] + rI[1][2] + rI[1][3];
        blockAcc[b * 256 + blockIdx.x] = ba2;
    }
    for (int i = tid; i < NBA / 2; i += 256) {
        unsigned v = ahp[i];
        if (v) {
            if (v & 0xFFFFu) atomicAdd(&ahist[b * NBA + 2 * i], v & 0xFFFFu);
            if (v >> 16)     atomicAdd(&ahist[b * NBA + 2 * i + 1], v >> 16);
        }
    }
}

// ---------- tailB(+A): per-block redundant params recompute + compact + cell list ----------
// grid (64, BN) x 256 threads: each block owns 1024 anchors of one image.
__global__ __launch_bounds__(256) void tailB_kernel(
    const float* __restrict__ conf, const float4* __restrict__ bboxp,
    const float4* __restrict__ anchors, const float4* __restrict__ tboxes,
    const int* __restrict__ tlabels,
    const unsigned long long* __restrict__ gbest,
    const BlockAcc* __restrict__ blockAcc,
    const unsigned* __restrict__ ahist, const unsigned short* __restrict__ maxb,
    ImgParams* __restrict__ params,
    float* __restrict__ list, unsigned* __restrict__ listCnt)
{
    __shared__ unsigned hist[NBA];         // local copy; undo applied locally
    __shared__ unsigned scanL[256];
    __shared__ float4 tbS[TN];
    __shared__ int tlS[TN];
    __shared__ float taS[TN];
    __shared__ unsigned gaS[TN];
    __shared__ float dps[TN], dbb[TN];
    __shared__ int dnp[TN], dnn[TN];
    __shared__ unsigned undoS[TN], undoIR[TN];
    __shared__ double sdblP[4], sdblB[4];
    __shared__ unsigned sunsP[4], sunsB[4];
    __shared__ double s_pos, s_bbox;
    __shared__ unsigned s_np, s_nn, s_k, s_act, s_ve, s_undoCnt, s_irCnt;
    __shared__ int candS[1024];
    __shared__ unsigned bufS[BUFC];
    __shared__ unsigned s_cnt, s_bcnt, s_gbase;

    int b = blockIdx.y, tid = threadIdx.x;
    int wv = tid >> 6, ln = tid & 63;

    for (int i = tid; i < NBA; i += 256) hist[i] = ahist[b * NBA + i];
    if (tid < TN) {
        gaS[tid] = ~(unsigned)(gbest[b * TN + tid] & 0xFFFFFFFFull);
        float4 T = tboxes[b * TN + tid];
        tbS[tid] = T; tlS[tid] = tlabels[b * TN + tid]; taS[tid] = box_area(T);
        dps[tid] = 0.f; dbb[tid] = 0.f; dnp[tid] = 0; dnn[tid] = 0;
    }
    if (tid == 0) { s_undoCnt = 0u; s_irCnt = 0u; s_cnt = 0u; }
    __syncthreads();

    // ---- phase A (redundant per block, deterministic): force-match fix ----
    if (tid < TN) {
        bool doit = true;
        unsigned ga = gaS[tid];
        for (int u = 0; u < tid; ++u) if (gaS[u] == ga) doit = false;   // dedupe
        if (doit) {
            size_t idx = (size_t)b * AN + ga;
            float4 ab = anchors[ga];
            float aa = box_area(ab);
            float best = -1.f; int bt = 0;
#pragma unroll
            for (int t = 0; t < TN; ++t) {
                float iou = iou_rcp(ab, aa, tbS[t], taS[t]);   // bit-identical to main
                if (iou > best) { best = iou; bt = t; }
            }
            if (best < 0.5f) {
                int label = tlS[bt];
                float c[CN];
                float inv = row_prep(conf + idx * CN, c);
                float fsv = 0.f;
#pragma unroll
                for (int j = 0; j < CN; ++j) fsv += cell_focal(c[j], inv, j == label);
                dps[tid] = fsv;
                dbb[tid] = bbox_per(bboxp[idx], tbS[bt]);
                dnp[tid] = 1;
                if (best < 0.4f) {   // was counted neg: undo locally
                    unsigned enc = maxb[idx];        // bin+1
                    atomicSub(&hist[enc - 1u], 1u);
                    dnn[tid] = -1;
                    unsigned p = atomicAdd(&s_undoCnt, 1u);
                    undoS[p] = ga;                   // global anchor idx to exclude
                }
            }
        }
    }
    __syncthreads();

    // ---- phase B: totals (256 threads, 1 BlockAcc each; same tree/order) ----
    {
        BlockAcc ba = blockAcc[b * 256 + tid];
        double ps = (double)ba.pos_sum, bs = (double)ba.bbox_sum;
        unsigned np = ba.np, nn = ba.nn;
#pragma unroll
        for (int off = 32; off; off >>= 1) {
            ps += __shfl_down(ps, off, 64);
            bs += __shfl_down(bs, off, 64);
            np += __shfl_down(np, off, 64);
            nn += __shfl_down(nn, off, 64);
        }
        if (ln == 0) { sdblP[wv] = ps; sdblB[wv] = bs; sunsP[wv] = np; sunsB[wv] = nn; }
    }
    __syncthreads();
    if (tid == 0) {
        double dp = 0, db = 0; int cp = 0, cn = 0;
        for (int i = 0; i < TN; ++i) { dp += dps[i]; db += dbb[i]; cp += dnp[i]; cn += dnn[i]; }
        s_pos = sdblP[0] + sdblP[1] + sdblP[2] + sdblP[3] + dp;
        s_bbox = sdblB[0] + sdblB[1] + sdblB[2] + sdblB[3] + db;
        unsigned NP = (unsigned)((int)(sunsP[0] + sunsP[1] + sunsP[2] + sunsP[3]) + cp);
        unsigned NN = (unsigned)((int)(sunsB[0] + sunsB[1] + sunsB[2] + sunsB[3]) + cn);
        s_np = NP; s_nn = NN;
        unsigned k = min(3u * NP, NN);
        s_k = k;
        s_act = (NN > 0 && k > 0) ? 1u : 0u;
        s_ve = 0u;
    }
    __syncthreads();

    if (s_act) {
        unsigned k = s_k;
        // ---- phase C: anchor-max threshold (2048 bins, 8/thread, suffix scan) ----
        unsigned l8[8], cc = 0;
#pragma unroll
        for (int q = 0; q < 8; ++q) { l8[q] = hist[tid * 8 + q]; cc += l8[q]; }
        scanL[tid] = cc;
        __syncthreads();
        for (int off = 1; off < 256; off <<= 1) {
            unsigned v = (tid + off < 256) ? scanL[tid + off] : 0u;
            __syncthreads();
            scanL[tid] += v;
            __syncthreads();
        }
        {
            unsigned above = (tid < 255) ? scanL[tid + 1] : 0u;
            if (above < k && above + cc >= k) {
                unsigned a2 = above;
                for (int q = 7; q >= 0; --q) {
                    unsigned bc = l8[q];
                    if (a2 + bc >= k) { s_ve = ((unsigned)(tid * 8 + q) << 21) | 1u; break; }
                    a2 += bc;
                }
            }
        }
        __syncthreads();
    }
    if (blockIdx.x == 0 && tid == 0) {
        ImgParams P;
        P.pos = s_pos; P.bbox = s_bbox;
        P.np = s_np; P.nn = s_nn; P.k = s_k; P.ve = s_ve; P.act = s_act;
        params[b] = P;
    }
    if (!s_act) return;   // uniform per block

    unsigned ve = s_ve;
    unsigned vbits = ve >> 1;
    unsigned short tb16 = (unsigned short)((ve >> 21) + 1u);   // candidate iff enc16 >= tb16
    int base = blockIdx.x * 1024;

    // filter undo list to this block's range (usually 0-1 entries)
    unsigned uc = s_undoCnt;
    if (tid < uc) {
        unsigned e = undoS[tid];
        if (e >= (unsigned)base && e < (unsigned)(base + 1024)) {
            unsigned p = atomicAdd(&s_irCnt, 1u);
            undoIR[p] = e;
        }
    }
    __syncthreads();
    unsigned ir = s_irCnt;

    const ushort4* mb4 = (const ushort4*)(maxb + (size_t)b * AN + base);
    ushort4 m4 = mb4[tid];
    unsigned c0 = (m4.x >= tb16), c1 = (m4.y >= tb16), c2 = (m4.z >= tb16), c3 = (m4.w >= tb16);
    int a0 = base + tid * 4;
    for (unsigned u = 0; u < ir; ++u) {     // exclude undone forced anchors
        unsigned e = undoIR[u];
        if (e == (unsigned)a0)          c0 = 0;
        else if (e == (unsigned)a0 + 1) c1 = 0;
        else if (e == (unsigned)a0 + 2) c2 = 0;
        else if (e == (unsigned)a0 + 3) c3 = 0;
    }
    unsigned cnt = c0 + c1 + c2 + c3;
    unsigned pos = 0;
    if (cnt) pos = atomicAdd(&s_cnt, cnt);
    if (c0) candS[pos++] = a0 + 0;
    if (c1) candS[pos++] = a0 + 1;
    if (c2) candS[pos++] = a0 + 2;
    if (c3) candS[pos++] = a0 + 3;
    __syncthreads();
    unsigned n = s_cnt;

    for (unsigned cbase = 0; cbase < n; cbase += CHUNK) {
        if (tid == 0) s_bcnt = 0u;
        __syncthreads();
        unsigned i = cbase + tid;
        if (i < n) {
            int a = candS[i];
            size_t idx = (size_t)b * AN + a;
            float c[CN];
            float inv = row_prep(conf + idx * CN, c);
#pragma unroll
            for (int j = 0; j < CN; ++j) {
                float fo = cell_focal(c[j], inv, false);
                unsigned bits = focal_bits(fo);
                bool hit = bits >= vbits;
                unsigned long long msk = __ballot(hit);
                if (hit) {
                    unsigned pre = mbcnt64(msk);
                    unsigned bb = 0;
                    if (pre == 0) bb = atomicAdd(&s_bcnt, (unsigned)__popcll(msk));
                    bb = __shfl(bb, (int)(__ffsll((long long)msk) - 1), 64);
                    bufS[bb + pre] = bits;   // canonicalized focal bits
                }
            }
        }
        __syncthreads();
        unsigned ccnt = s_bcnt;
        if (ccnt) {
            if (tid == 0) s_gbase = atomicAdd(&listCnt[b * 16], ccnt);  // 64B-padded counter
            __syncthreads();
            unsigned gb = s_gbase;
            for (unsigned j2 = tid; j2 < ccnt; j2 += 256) {
                unsigned p = gb + j2;
                if (p < (unsigned)LCAPG)
                    list[(size_t)b * LCAPG + p] = __uint_as_float(bufS[j2]);
            }
        }
        __syncthreads();
    }
}

// ---------- tailC: top-k select over compact list + per-image result + average ----------
__global__ __launch_bounds__(1024) void tailC_kernel(
    const float* __restrict__ list, const unsigned* __restrict__ listCnt,
    const ImgParams* __restrict__ params,
    double* __restrict__ imgRes, unsigned* __restrict__ ctr,
    float* __restrict__ out)
{
    __shared__ float lcache[LCAP];      // 40 KB
    __shared__ unsigned hist[4096];
    __shared__ unsigned scan_[1024];
    __shared__ double sdbl[16];
    __shared__ double s_sumAbove;
    __shared__ unsigned s_b1, s_rem, s_b2, s_rem2, s_b3, s_rem3;

    int b = blockIdx.x, tid = threadIdx.x;
    int wv = tid >> 6, ln = tid & 63;
    ImgParams P = params[b];
    double topk = 0.0;

    if (P.act) {
        unsigned n = min(listCnt[b * 16], (unsigned)LCAPG);
        const float* gl = list + (size_t)b * LCAPG;
        bool inL = (n <= (unsigned)LCAP);
        if (inL) for (unsigned i = tid; i < n; i += 1024) lcache[i] = gl[i];
        if (tid == 0) { s_b1 = 0; s_rem = 0; s_b3 = 0; s_rem3 = 0; }
        for (int i = tid; i < 4096; i += 1024) hist[i] = 0u;
        __syncthreads();

        // pass 0: 2048-bin hist over top bits (focal >= 0 -> bits>>20 < 2048)
        for (unsigned i = tid; i < n; i += 1024) {
            unsigned bits = __float_as_uint(inL ? lcache[i] : gl[i]);
            atomicAdd(&hist[bits >> 20], 1u);
        }
        __syncthreads();

        // select b1 (suffix scan, 2 bins/thread)
        unsigned lc0 = hist[tid * 2], lc1 = hist[tid * 2 + 1];
        unsigned cc = lc0 + lc1;
        scan_[tid] = cc;
        __syncthreads();
        for (int off = 1; off < 1024; off <<= 1) {
            unsigned v = (tid + off < 1024) ? scan_[tid + off] : 0u;
            __syncthreads();
            scan_[tid] += v;
            __syncthreads();
        }
        {
            unsigned total = scan_[0];
            unsigned above = (tid < 1023) ? scan_[tid + 1] : 0u;
            unsigned r = min(P.k, total);
            if (r > 0 && above < r && above + cc >= r) {
                if (above + lc1 >= r) { s_b1 = (unsigned)(tid * 2 + 1); s_rem = r - above; }
                else { s_b1 = (unsigned)(tid * 2); s_rem = r - above - lc1; }
            }
        }
        __syncthreads();
        unsigned b1 = s_b1, rem = s_rem;

        // pass 1: sumAbove (hi > b1) + 12-bit sub-hist for hi == b1
        for (int i = tid; i < 4096; i += 1024) hist[i] = 0u;
        __syncthreads();
        double sA = 0.0;
        for (unsigned i = tid; i < n; i += 1024) {
            float v = inL ? lcache[i] : gl[i];
            unsigned bits = __float_as_uint(v);
            unsigned hi = bits >> 20;
            if (hi > b1) sA += (double)v;
            else if (hi == b1) atomicAdd(&hist[(bits >> 8) & 0xFFFu], 1u);
        }
#pragma unroll
        for (int off = 32; off; off >>= 1) sA += __shfl_down(sA, off, 64);
        if (ln == 0) sdbl[wv] = sA;
        __syncthreads();
        if (tid == 0) {
            double tt = 0;
            for (int w = 0; w < 16; ++w) tt += sdbl[w];
            s_sumAbove = tt;
        }
        __syncthreads();
        double sumAbove = s_sumAbove;

        if (rem == 0) {
            topk = sumAbove;
        } else {
            // select b2 from 4096-bin hist (4 bins/thread)
            unsigned l4[4], cc4 = 0;
#pragma unroll
            for (int q = 0; q < 4; ++q) { l4[q] = hist[tid * 4 + q]; cc4 += l4[q]; }
            scan_[tid] = cc4;
            __syncthreads();
            for (int off = 1; off < 1024; off <<= 1) {
                unsigned v = (tid + off < 1024) ? scan_[tid + off] : 0u;
                __syncthreads();
                scan_[tid] += v;
                __syncthreads();
            }
            {
                unsigned total = scan_[0];
                unsigned above = (tid < 1023) ? scan_[tid + 1] : 0u;
                unsigned r = min(rem, total);
                if (above < r && above + cc4 >= r) {
                    unsigned a2 = above;
                    for (int i = 3; i >= 0; --i) {
                        unsigned bc = l4[i];
                        if (a2 + bc >= r) { s_b2 = (unsigned)(tid * 4 + i); s_rem2 = r - a2; break; }
                        a2 += bc;
                    }
                }
            }
            __syncthreads();
            unsigned b2 = s_b2, rem2 = s_rem2;
            if (tid < 256) hist[tid] = 0u;
            __syncthreads();

            // pass 2: sMid (sub > b2) + 8-bit hist for sub == b2
            double sMid = 0.0;
            for (unsigned i = tid; i < n; i += 1024) {
                float v = inL ? lcache[i] : gl[i];
                unsigned bits = __float_as_uint(v);
                if ((bits >> 20) != b1) continue;
                unsigned sub = (bits >> 8) & 0xFFFu;
                if (sub > b2) sMid += (double)v;
                else if (sub == b2) atomicAdd(&hist[bits & 0xFFu], 1u);
            }
            __syncthreads();
            if (tid < 256) scan_[tid] = hist[tid];
            __syncthreads();
            for (int off = 1; off < 256; off <<= 1) {
                unsigned v = 0;
                if (tid < 256 && tid + off < 256) v = scan_[tid + off];
                __syncthreads();
                if (tid < 256) scan_[tid] += v;
                __syncthreads();
            }
            if (tid < 256) {
                unsigned above8 = (tid < 255) ? scan_[tid + 1] : 0u;
                unsigned c8 = hist[tid];
                if (above8 < rem2 && above8 + c8 >= rem2) { s_b3 = (unsigned)tid; s_rem3 = rem2 - above8; }
            }
            __syncthreads();
            unsigned b3 = s_b3, rem3 = s_rem3;

            // pass 3: s3 for (b1,b2, low > b3)
            double s3 = 0.0;
            for (unsigned i = tid; i < n; i += 1024) {
                float v = inL ? lcache[i] : gl[i];
                unsigned bits = __float_as_uint(v);
                if ((bits >> 20) == b1 && ((bits >> 8) & 0xFFFu) == b2 && (bits & 0xFFu) > b3)
                    s3 += (double)v;
            }
            double tot = sMid + s3;
#pragma unroll
            for (int off = 32; off; off >>= 1) tot += __shfl_down(tot, off, 64);
            if (ln == 0) sdbl[wv] = tot;
            __syncthreads();
            if (tid == 0) {
                double totAll = 0;
                for (int w = 0; w < 16; ++w) totAll += sdbl[w];
                unsigned vb3 = (b1 << 20) | (b2 << 8) | b3;
                topk = sumAbove + totAll + (double)rem3 * (double)__uint_as_float(vb3);
            }
        }
    }

    // ---- per-image result + last-block average ----
    if (tid == 0) {
        double confl;
        if (P.act) confl = (P.pos + topk) / (double)max(P.np + P.k, 1u);
        else       confl = P.pos / (double)max(P.np, 1u);
        imgRes[b * 2 + 0] = confl;
        imgRes[b * 2 + 1] = P.bbox / (double)max(P.np, 1u);
        __threadfence();
        unsigned prev = atomicAdd(ctr, 1u);
        if (prev == BN - 1) {
            __threadfence();
            double cs = 0, bs = 0;
            for (int i = 0; i < BN; ++i) { cs += imgRes[i * 2]; bs += imgRes[i * 2 + 1]; }
            cs /= BN; bs /= BN;
            out[0] = (float)(cs + bs);
            out[1] = (float)cs;
            out[2] = (float)bs;
        }
    }
}

extern "C" void kernel_launch(void* const* d_in, const int* in_sizes, int n_in,
                              void* d_out, int out_size, void* d_ws, size_t ws_size,
                              hipStream_t stream)
{
    (void)in_sizes; (void)n_in; (void)out_size; (void)ws_size;
    const float*  conf    = (const float*)d_in[0];
    const float4* bboxp   = (const float4*)d_in[1];
    const float4* anchors = (const float4*)d_in[2];
    const float4* tboxes  = (const float4*)d_in[3];
    const int*    tlabels = (const int*)d_in[4];
    float* out = (float*)d_out;
    char* ws = (char*)d_ws;
    size_t off = 0;
    auto alloc = [&](size_t bytes) -> void* {
        void* p = (void*)(ws + off);
        off = (off + bytes + 255) & ~(size_t)255;
        return p;
    };
    unsigned short* maxb = (unsigned short*)alloc((size_t)BN * AN * 2);
    float*     list     = (float*)alloc((size_t)BN * LCAPG * 4);
    BlockAcc*  blockAcc = (BlockAcc*)alloc((size_t)BN * 256 * sizeof(BlockAcc));
    double*    imgRes   = (double*)alloc((size_t)BN * 2 * 8);
    ImgParams* params   = (ImgParams*)alloc((size_t)BN * sizeof(ImgParams));
    size_t zstart = off;
    unsigned long long* gbest = (unsigned long long*)alloc((size_t)BN * TN * 8);
    unsigned* ahist   = (unsigned*)alloc((size_t)BN * NBA * 4);
    unsigned* ctr     = (unsigned*)alloc(256);
    unsigned* listCnt = (unsigned*)alloc((size_t)BN * 16 * 4);   // 64B stride per image
    size_t zbytes = off - zstart;
    hipMemsetAsync(ws + zstart, 0, zbytes, stream);

    dim3 gridA(AN / 256, BN);
    main_kernel<<<gridA, 256, 0, stream>>>(conf, bboxp, anchors, tboxes, tlabels,
                                           gbest, ahist, maxb, blockAcc);
    tailB_kernel<<<dim3(64, BN), 256, 0, stream>>>(conf, bboxp, anchors, tboxes, tlabels,
                                                   gbest, blockAcc, ahist, maxb,
                                                   params, list, listCnt);
    tailC_kernel<<<BN, 1024, 0, stream>>>(list, listCnt, params, imgRes, ctr, out);
}